// Round 6
// baseline (105.426 us; speedup 1.0000x reference)
//
#include <hip/hip_runtime.h>

// Problem constants (from reference setup_inputs)
#define B_  16
#define T_  4096
#define C_  512
#define K_  4
#define C4_ (C_ / 4)          // 128 float4 columns

// Fused kernel geometry: block = (b, 32-channel tile), owns all of T.
#define NW_     8             // waves per block
#define SUBW_   8             // subchunks per wave
#define NSUB_   (NW_ * SUBW_) // 64 subchunks per chunk
#define LSUB_   8             // timesteps per thread per chunk
#define CHUNK_  (NSUB_ * LSUB_)  // 512 timesteps per iteration
#define NCHUNK_ (T_ / CHUNK_)    // 8 iterations
#define CT_     32            // channels per block tile
#define NCT_    (C_ / CT_)    // 16 tiles -> grid = 16*16 = 256 blocks

typedef float f4 __attribute__((ext_vector_type(4)));

__device__ __forceinline__ float sigmoid_clamp(float la) {
    float av = 1.0f / (1.0f + expf(-la));
    return fminf(fmaxf(av, 1e-4f), 1.0f - 1e-4f);
}

__device__ __forceinline__ f4 shflup4(f4 v, int delta) {
    f4 r;
    r.x = __shfl_up(v.x, delta, 64);
    r.y = __shfl_up(v.y, delta, 64);
    r.z = __shfl_up(v.z, delta, 64);
    r.w = __shfl_up(v.w, delta, 64);
    return r;
}

// One x read, one out write, no workspace. Carry chain lives in registers
// (Gw) + closed-form A-power tables in LDS; cross-wave combine via a small
// double-buffered LDS table with ONE raw barrier per chunk (lgkmcnt only,
// vmcnt stays in flight so the next-chunk prefetch spans the barrier).
__global__ __launch_bounds__(512, 2) void ema_fused(
    const f4* __restrict__ x4,
    const float* __restrict__ logit_alpha,
    const f4* __restrict__ ml4,
    f4* __restrict__ out4)
{
    __shared__ f4 POW8[9][K_][8];     // POW8[s][k][c4l]  = a^(8s),  s=0..8
    __shared__ f4 POW64[9][K_][8];    // POW64[w][k][c4l] = a^(64w), w=0..8
    __shared__ f4 WT[2][NW_][K_][8];  // per-wave chunk totals, double-buffered

    const int tid  = threadIdx.x;
    const int wv   = tid >> 6;        // wave 0..7
    const int lane = tid & 63;
    const int subl = lane >> 3;       // subchunk within wave, 0..7
    const int c4l  = lane & 7;        // float4 lane within 32-ch tile, 0..7
    const int sub  = (wv << 3) | subl;// global subchunk 0..63

    const int b  = blockIdx.x >> 4;
    const int ct = blockIdx.x & 15;
    const int c4 = ct * 8 + c4l;      // global float4 column 0..127

    // ---- per-thread parameters (4 channels wide) ----
    f4 one = {1.f, 1.f, 1.f, 1.f};
    f4 zero = {0.f, 0.f, 0.f, 0.f};
    f4 a[K_], oma[K_], m[K_];
#pragma unroll
    for (int k = 0; k < K_; ++k) {
        f4 la = ((const f4*)logit_alpha)[k * C4_ + c4];
        f4 av;
        av.x = sigmoid_clamp(la.x); av.y = sigmoid_clamp(la.y);
        av.z = sigmoid_clamp(la.z); av.w = sigmoid_clamp(la.w);
        a[k] = av; oma[k] = one - av;
    }
    // softmax mix weights: mix_logits[c][0..K) is one f4 per channel
#pragma unroll
    for (int ci = 0; ci < 4; ++ci) {
        f4 ml = ml4[c4 * 4 + ci];
        float mx = fmaxf(fmaxf(ml.x, ml.y), fmaxf(ml.z, ml.w));
        float e0 = expf(ml.x - mx), e1 = expf(ml.y - mx);
        float e2 = expf(ml.z - mx), e3 = expf(ml.w - mx);
        float inv = 1.0f / (e0 + e1 + e2 + e3);
        m[0][ci] = e0 * inv; m[1][ci] = e1 * inv;
        m[2][ci] = e2 * inv; m[3][ci] = e3 * inv;
    }

    // ---- one-time A-power tables (32 builder threads) ----
    if (tid < 32) {
        const int kk = tid >> 3, cc = tid & 7;
        f4 av = a[kk];
        f4 A8 = av * av; A8 = A8 * A8; A8 = A8 * A8;       // a^8
        f4 cur = one;
        POW8[0][kk][cc] = cur;
#pragma unroll
        for (int s = 1; s <= 8; ++s) { cur = cur * A8; POW8[s][kk][cc] = cur; }
        f4 A64 = cur;                                       // a^64
        cur = one;
        POW64[0][kk][cc] = cur;
#pragma unroll
        for (int w = 1; w <= 8; ++w) { cur = cur * A64; POW64[w][kk][cc] = cur; }
    }
    __syncthreads();

    // ---- persistent per-thread state ----
    const size_t basein = (size_t)b * T_ * C4_ + c4;
    f4 x0 = x4[basein];                       // x[b,0,c] (seed: y[-1] := x0)
    f4 Asub[K_], Gw[K_];                      // Gw = a^(64*wv) * G
#pragma unroll
    for (int k = 0; k < K_; ++k) {
        Asub[k] = POW8[subl][k][c4l];
        Gw[k]   = POW64[wv][k][c4l] * x0;
    }

    const int trow = sub * LSUB_;             // thread's first t within chunk
    f4 xc[LSUB_];
#pragma unroll
    for (int i = 0; i < LSUB_; ++i)
        xc[i] = __builtin_nontemporal_load(&x4[basein + (size_t)(trow + i) * C4_]);

#pragma unroll 1
    for (int ch = 0; ch < NCHUNK_; ++ch) {
        // prefetch next chunk (stays in flight across the barrier below)
        f4 xn[LSUB_];
        if (ch + 1 < NCHUNK_) {
#pragma unroll
            for (int i = 0; i < LSUB_; ++i)
                xn[i] = __builtin_nontemporal_load(
                    &x4[basein + (size_t)((ch + 1) * CHUNK_ + trow + i) * C4_]);
        }

        // zero-init scan over own 8 steps
        f4 s[K_];
#pragma unroll
        for (int k = 0; k < K_; ++k) s[k] = zero;
#pragma unroll
        for (int i = 0; i < LSUB_; ++i) {
            f4 xv = xc[i];
#pragma unroll
            for (int k = 0; k < K_; ++k) s[k] = a[k] * s[k] + oma[k] * xv;
        }

        // wave-level Hillis-Steele scan over subl (multiplier a^(8*dd))
#pragma unroll
        for (int st = 0; st < 3; ++st) {
            const int dd = 1 << st;
#pragma unroll
            for (int k = 0; k < K_; ++k) {
                f4 Mv = POW8[dd][k][c4l];
                f4 r  = shflup4(s[k], dd * 8);
                f4 t2 = s[k] + Mv * r;
                s[k] = (subl >= dd) ? t2 : s[k];
            }
        }
        // wave-local exclusive prefix for own subchunk
        f4 Ils[K_];
#pragma unroll
        for (int k = 0; k < K_; ++k) {
            f4 r = shflup4(s[k], 8);
            Ils[k] = (subl >= 1) ? r : zero;
        }

        const int pb = ch & 1;
        if (subl == 7) {
#pragma unroll
            for (int k = 0; k < K_; ++k) WT[pb][wv][k][c4l] = s[k];
        }
        // barrier with LDS-only drain: vmcnt (prefetch) stays outstanding
        asm volatile("s_waitcnt lgkmcnt(0)" ::: "memory");
        __builtin_amdgcn_s_barrier();

        // cross-wave Horner: P = prefix into own wave, acc -> chunk total
        f4 P[K_], acc[K_], A64r[K_];
#pragma unroll
        for (int k = 0; k < K_; ++k) {
            P[k] = zero; acc[k] = zero; A64r[k] = POW64[1][k][c4l];
        }
#pragma unroll
        for (int w = 0; w < NW_; ++w) {
#pragma unroll
            for (int k = 0; k < K_; ++k) {
                if (w == wv) P[k] = acc[k];
                acc[k] = A64r[k] * acc[k] + WT[pb][w][k][c4l];
            }
        }

        // carry entering own subchunk, rescan from registers, mix, store
        f4 y[K_];
#pragma unroll
        for (int k = 0; k < K_; ++k) y[k] = Asub[k] * (Gw[k] + P[k]) + Ils[k];

        const size_t ob = basein + (size_t)(ch * CHUNK_ + trow) * C4_;
#pragma unroll
        for (int i = 0; i < LSUB_; ++i) {
            f4 xv = xc[i];
            f4 o = zero;
#pragma unroll
            for (int k = 0; k < K_; ++k) {
                y[k] = a[k] * y[k] + oma[k] * xv;
                o = o + m[k] * y[k];
            }
            __builtin_nontemporal_store(o, &out4[ob + (size_t)i * C4_]);
        }

        // advance running carry: Gw = a^512 * Gw + a^(64*wv) * chunk_total
#pragma unroll
        for (int k = 0; k < K_; ++k)
            Gw[k] = POW64[NW_][k][c4l] * Gw[k] + POW64[wv][k][c4l] * acc[k];

        if (ch + 1 < NCHUNK_) {
#pragma unroll
            for (int i = 0; i < LSUB_; ++i) xc[i] = xn[i];
        }
    }
}

extern "C" void kernel_launch(void* const* d_in, const int* in_sizes, int n_in,
                              void* d_out, int out_size, void* d_ws, size_t ws_size,
                              hipStream_t stream) {
    const float* x           = (const float*)d_in[0];
    const float* logit_alpha = (const float*)d_in[1];
    const float* mix_logits  = (const float*)d_in[2];
    float* out = (float*)d_out;

    ema_fused<<<B_ * NCT_, 512, 0, stream>>>((const f4*)x, logit_alpha,
                                             (const f4*)mix_logits, (f4*)out);
}